// Round 11
// baseline (688.481 us; speedup 1.0000x reference)
//
#include <hip/hip_runtime.h>
#include <math.h>

#define B_ 16
#define L_ 4096
#define H_ 8
#define E_ 64
#define C_ 512     // H*E
#define K_ 24
#define NT 256
#define RPAD 257   // padded row stride (float2 units) for the 16x256 LDS matrix
#define WSZ 4112   // 16*RPAD, per-channel FFT work size (float2)

__device__ __forceinline__ float2 cmul(float2 a, float2 b) {
    return make_float2(a.x * b.x - a.y * b.y, a.x * b.y + a.y * b.x);
}
__device__ __forceinline__ float2 cadd(float2 a, float2 b) { return make_float2(a.x + b.x, a.y + b.y); }
__device__ __forceinline__ float2 csub(float2 a, float2 b) { return make_float2(a.x - b.x, a.y - b.y); }

// barrier that orders LDS only: each wave drains its own lgkmcnt, then
// s_barrier -> all waves' LDS ops retired; vmcnt loads stay in flight
__device__ __forceinline__ void bar_lds() {
    asm volatile("s_waitcnt lgkmcnt(0)" ::: "memory");
    __builtin_amdgcn_s_barrier();
}

// 16-point DIF FFT, natural-order input; output: X[k] = a[br4[k]]
__device__ __forceinline__ void fft16(float2 a[16]) {
    const float r2 = 0.70710678118654752f;
    const float c1 = 0.92387953251128676f;  // cos(pi/8)
    const float s1 = 0.38268343236508977f;  // sin(pi/8)
    const float2 W16[8] = {
        make_float2(1.f, 0.f),  make_float2(c1, -s1),  make_float2(r2, -r2),  make_float2(s1, -c1),
        make_float2(0.f, -1.f), make_float2(-s1, -c1), make_float2(-r2, -r2), make_float2(-c1, -s1)};
    #pragma unroll
    for (int j = 0; j < 8; ++j) {
        float2 u = a[j], v = a[j + 8];
        a[j]     = cadd(u, v);
        a[j + 8] = cmul(csub(u, v), W16[j]);
    }
    #pragma unroll
    for (int b = 0; b < 16; b += 8)
        #pragma unroll
        for (int j = 0; j < 4; ++j) {
            float2 u = a[b + j], v = a[b + j + 4];
            a[b + j]     = cadd(u, v);
            a[b + j + 4] = cmul(csub(u, v), W16[2 * j]);
        }
    #pragma unroll
    for (int b = 0; b < 16; b += 4)
        #pragma unroll
        for (int j = 0; j < 2; ++j) {
            float2 u = a[b + j], v = a[b + j + 2];
            a[b + j]     = cadd(u, v);
            a[b + j + 2] = cmul(csub(u, v), W16[4 * j]);
        }
    #pragma unroll
    for (int b = 0; b < 16; b += 2) {
        float2 u = a[b], v = a[b + 1];
        a[b]     = cadd(u, v);
        a[b + 1] = csub(u, v);
    }
}

// ---------------- zero scratch ----------------
__global__ __launch_bounds__(256) void k_zero(float* __restrict__ p, int n) {
    int i = blockIdx.x * 256 + threadIdx.x;
    if (i < n) p[i] = 0.f;
}

// ---------------- fused forward FFT + cross-spectrum: ONE CHANNEL PER BLOCK ----------------
// Rounds 7/8 post-mortem: 1 vs 2 blocks/CU and 16.8M vs 33.6M load-requests
// gave IDENTICAL ~275us -> bound by wide-barrier lockstep (equal total
// barrier-crossings ~295K both). This version minimizes the barrier domain:
// 256 threads / 1 channel / 4-wave barriers, 35KB LDS -> 4 independent
// blocks/CU; when one block barriers, three others compute.
// Structural wins: single-channel layout is stride-8B everywhere -> ZERO bank
// conflicts by construction; no cross-group reduction (atomics direct, no
// trailing barrier); staging in two 8-tau sub-rounds keeps live regs ~55 < 64.
// Channel pairs (c, c^1) load the same float2; the 16 blocks sharing each 64B
// line map to the same XCD (line index = id bits 3..6; XCD = id&7) -> L2 dedup.
// Conjugate symmetry: accumulate + atomics only bins 0..2048.
__global__ __launch_bounds__(256) void k_fft1(const float* __restrict__ q,
                                              const float* __restrict__ k,
                                              float* __restrict__ cross) {
    __shared__ float2 w[WSZ];         // 32.9 KB union: stg[0..4095] / RPAD work
    __shared__ float2 tw256[256];     // tw256[r1*16+m2] = W256^{m2*r1}
    const int br4[16] = {0, 8, 4, 12, 2, 10, 6, 14, 1, 9, 5, 13, 3, 11, 7, 15};
    const int t = threadIdx.x;

    // XCD-aware bijective decode: 8192 blocks; xcd = id&7 owns 2 whole batches
    int id = blockIdx.x;
    int wk = ((id & 7) << 10) | (id >> 3);
    int b  = wk >> 9;                 // 0..15
    int c  = wk & 511;                // channel

    {
        int r1 = t >> 4, m2 = t & 15;
        float sn, cs;
        sincospif((float)(r1 * m2) / 128.0f, &sn, &cs);
        tw256[t] = make_float2(cs, -sn);
    }

    const int comp = c & 1;
    const float* qb = q + (size_t)b * L_ * C_ + (c & ~1);
    const float* kb = k + (size_t)b * L_ * C_ + (c & ~1);

    // ---- stage z = q_c + i*k_c into w[tau], two 8-tau sub-rounds (32 regs live)
    #pragma unroll
    for (int sr = 0; sr < 2; ++sr) {
        float2 qv[8], kv[8];
        #pragma unroll
        for (int it = 0; it < 8; ++it) {
            int tau = (((sr << 3) + it) << 8) + t;
            qv[it] = *(const float2*)(qb + (size_t)tau * C_);
            kv[it] = *(const float2*)(kb + (size_t)tau * C_);
        }
        #pragma unroll
        for (int it = 0; it < 8; ++it) {
            int tau = (((sr << 3) + it) << 8) + t;
            float qc = comp ? qv[it].y : qv[it].x;
            float kc = comp ? kv[it].y : kv[it].x;
            w[tau] = make_float2(qc, kc);   // lane-stride 8B: conflict-free
        }
    }
    __syncthreads();

    // ---- phase-A gather (stride 8B, conflict-free) ----
    float2 a[16];
    #pragma unroll
    for (int n1 = 0; n1 < 16; ++n1)
        a[n1] = w[(n1 << 8) + t];
    bar_lds();   // all gathers retired before phase-A writes overwrite stg

    // ---- phase A ----
    fft16(a);
    {
        float snA, csA;
        sincospif((float)t / 2048.0f, &snA, &csA);
        const float2 w1 = make_float2(csA, -snA);
        float2 tw = w1;
        w[t] = a[0];                        // k1 = 0
        #pragma unroll
        for (int k1 = 1; k1 < 16; ++k1) {
            w[k1 * RPAD + t] = cmul(a[br4[k1]], tw);
            tw = cmul(tw, w1);
        }
    }
    __syncthreads();
    // ---- phase B (in-place, cells thread-exclusive) ----
    const int rowB = t >> 4, m2B = t & 15;
    #pragma unroll
    for (int m1 = 0; m1 < 16; ++m1) a[m1] = w[rowB * RPAD + (m1 << 4) + m2B];
    fft16(a);
    #pragma unroll
    for (int r1 = 0; r1 < 16; ++r1)
        w[rowB * RPAD + (r1 << 4) + m2B] = cmul(a[br4[r1]], tw256[(r1 << 4) + m2B]);
    __syncthreads();
    // ---- phase C ----
    const int k1C = t & 15, r1C = t >> 4;
    #pragma unroll
    for (int m2 = 0; m2 < 16; ++m2) a[m2] = w[k1C * RPAD + (r1C << 4) + m2];
    fft16(a);
    __syncthreads();
    #pragma unroll
    for (int r2 = 0; r2 < 16; ++r2)
        w[(r2 << 8) + t] = a[br4[r2]];      // (r1C<<4)|k1C == t: natural order
    bar_lds();

    // ---- unpack Z=Q+iK, accumulate S=Q*conj(K), half spectrum p in [0,2047] ----
    float accx[8], accy[8];
    #pragma unroll
    for (int r = 0; r < 8; ++r) {
        int p  = t + (r << 8);
        int pp = (L_ - p) & (L_ - 1);
        float2 A  = w[p];
        float2 Bv = w[pp];
        float Qr = 0.5f * (A.x + Bv.x);
        float Qi = 0.5f * (A.y - Bv.y);
        float Kr = 0.5f * (A.y + Bv.y);
        float Ki = 0.5f * (A.x - Bv.x);
        accx[r] = Qr * Kr - Qi * Ki;
        accy[r] = Qr * Ki + Qi * Kr;
    }
    float v2048 = (t == 0) ? w[2048].x * w[2048].y : 0.f;

    // ---- direct atomics (no reduction, no trailing barrier) ----
    float* crb = cross + (size_t)b * L_ * 2;
    #pragma unroll
    for (int r = 0; r < 8; ++r) {
        int p = t + (r << 8);
        atomicAdd(&crb[p * 2 + 0], accx[r]);
        atomicAdd(&crb[p * 2 + 1], accy[r]);
    }
    if (t == 0) atomicAdd(&crb[2 * 2048], v2048);
}

// ---------------- inverse FFT via conj-forward 3-phase radix-16 ----------------
// cross holds only bins 0..2048; upper half reconstructed via S(L-p)=conj(S(p)).
__global__ __launch_bounds__(256) void k_ifft(const float* __restrict__ cross,
                                              float* __restrict__ mv) {
    __shared__ float2 s[16 * RPAD];
    __shared__ float2 tw256[256];
    const int br4[16] = {0, 8, 4, 12, 2, 10, 6, 14, 1, 9, 5, 13, 3, 11, 7, 15};
    int t = threadIdx.x;
    int b = blockIdx.x;
    {
        int r1 = t >> 4, m2 = t & 15;
        float sn, cs;
        sincospif((float)(r1 * m2) / 128.0f, &sn, &cs);
        tw256[t] = make_float2(cs, -sn);
    }
    const float2* cr = (const float2*)cross + (size_t)b * L_;
    float2 a[16];
    #pragma unroll
    for (int n1 = 0; n1 < 16; ++n1) {
        int P = (n1 << 8) + t;
        int hi = P > 2048;
        float2 v = cr[hi ? (L_ - P) : P];
        // want a = conj(S(P)): P<=2048 -> conj(v); P>2048 -> S(P)=conj(v) -> a = v
        a[n1] = hi ? v : make_float2(v.x, -v.y);
    }
    // ---- phase A ----
    fft16(a);
    {
        float sn, cs;
        sincospif((float)t / 2048.0f, &sn, &cs);
        const float2 w1 = make_float2(cs, -sn);
        float2 tw = w1;
        s[t] = a[0];
        #pragma unroll
        for (int k1 = 1; k1 < 16; ++k1) {
            s[k1 * RPAD + t] = cmul(a[br4[k1]], tw);
            tw = cmul(tw, w1);
        }
    }
    __syncthreads();
    // ---- phase B ----
    const int rowB = t >> 4, m2B = t & 15;
    #pragma unroll
    for (int m1 = 0; m1 < 16; ++m1) a[m1] = s[rowB * RPAD + (m1 << 4) + m2B];
    fft16(a);
    #pragma unroll
    for (int r1 = 0; r1 < 16; ++r1)
        s[rowB * RPAD + (r1 << 4) + m2B] = cmul(a[br4[r1]], tw256[(r1 << 4) + m2B]);
    __syncthreads();
    // ---- phase C: write mv directly (k = r2*256 + t, coalesced) ----
    const int k1C = t & 15, r1C = t >> 4;
    #pragma unroll
    for (int m2 = 0; m2 < 16; ++m2) a[m2] = s[k1C * RPAD + (r1C << 4) + m2];
    fft16(a);
    const float scale = 1.0f / ((float)L_ * (float)C_);
    #pragma unroll
    for (int r2 = 0; r2 < 16; ++r2)
        mv[(size_t)b * L_ + (r2 << 8) + t] = a[br4[r2]].x * scale;
}

// ---------------- top-24 + per-batch softmax (register-resident, wave-shuffle) ----------------
__global__ __launch_bounds__(256) void k_topk(const float* __restrict__ mv,
                                              int* __restrict__ idx,
                                              float* __restrict__ wts) {
    __shared__ float wv[4];
    __shared__ int   wi[4];
    __shared__ int   idxL[K_];
    int tid = threadIdx.x;
    float vloc[16];
    #pragma unroll
    for (int r = 0; r < 16; ++r) {
        int tt = tid + (r << 8);
        float ssum = 0.f;
        for (int b = 0; b < B_; ++b) ssum += mv[(size_t)b * L_ + tt];
        vloc[r] = ssum;
    }
    int lane = tid & 63, w = tid >> 6;
    for (int i = 0; i < K_; ++i) {
        float best = -INFINITY; int bi = 1 << 30;
        #pragma unroll
        for (int r = 0; r < 16; ++r) {
            float v = vloc[r]; int ii = tid + (r << 8);
            if (v > best || (v == best && ii < bi)) { best = v; bi = ii; }
        }
        #pragma unroll
        for (int off = 32; off > 0; off >>= 1) {
            float ov = __shfl_down(best, off);
            int   oi = __shfl_down(bi, off);
            if (ov > best || (ov == best && oi < bi)) { best = ov; bi = oi; }
        }
        if (lane == 0) { wv[w] = best; wi[w] = bi; }
        __syncthreads();
        if (tid == 0) {
            float bb = wv[0]; int bj = wi[0];
            for (int j = 1; j < 4; ++j)
                if (wv[j] > bb || (wv[j] == bb && wi[j] < bj)) { bb = wv[j]; bj = wi[j]; }
            idxL[i] = bj; idx[i] = bj;
        }
        __syncthreads();
        int win = idxL[i];
        #pragma unroll
        for (int r = 0; r < 16; ++r)
            if (win == tid + (r << 8)) vloc[r] = -INFINITY;
    }
    if (tid < B_) {
        int b = tid;
        float ww[K_]; float wm = -INFINITY;
        for (int i = 0; i < K_; ++i) { ww[i] = mv[(size_t)b * L_ + idxL[i]]; wm = fmaxf(wm, ww[i]); }
        float ssum = 0.f;
        for (int i = 0; i < K_; ++i) { ww[i] = expf(ww[i] - wm); ssum += ww[i]; }
        float inv = 1.f / ssum;
        for (int i = 0; i < K_; ++i) wts[b * K_ + i] = ww[i] * inv;
    }
}

// ---------------- 24-tap circulant gather-sum, LDS tau-ring version ----------------
__global__ __launch_bounds__(256) void k_agg(const float* __restrict__ vals,
                                             const int* __restrict__ idx,
                                             const float* __restrict__ wts,
                                             float* __restrict__ out) {
    __shared__ float4 sv[L_];      // 64 KB ring: 2 blocks/CU
    __shared__ int   di[K_];
    __shared__ float dw[K_];
    const int tid = threadIdx.x;
    // XCD-aware bijective decode: 2048 blocks; xcd = id&7 owns work [xcd*256, xcd*256+256)
    int id = blockIdx.x;
    int wk = ((id & 7) << 8) | (id >> 3);
    int b  = wk >> 7;              // 0..15 (2 batches per XCD)
    int c0 = (wk & 127) << 2;      // channel-quad start

    if (tid < K_) { di[tid] = idx[tid]; dw[tid] = wts[b * K_ + tid]; }

    // ---- stage: 16 iters x 256 lanes x 16B, LDS dest linear (wave-uniform base + lane*16)
    const float* gbase = vals + (size_t)b * L_ * C_ + c0;
    #pragma unroll
    for (int it = 0; it < 16; ++it) {
        int tau = (it << 8) + tid;
        const float* g = gbase + (size_t)tau * C_;
        float4* l = &sv[(it << 8) + ((tid >> 6) << 6)];   // wave-uniform within each wave
        __builtin_amdgcn_global_load_lds(
            (const __attribute__((address_space(1))) uint32_t*)g,
            (__attribute__((address_space(3))) uint32_t*)l,
            16, 0, 0);
    }
    __syncthreads();   // drains vmcnt before barrier

    // taps/weights to registers (fully-unrolled static indexing)
    int   dir[K_]; float dwr[K_];
    #pragma unroll
    for (int i = 0; i < K_; ++i) { dir[i] = di[i]; dwr[i] = dw[i]; }

    float* obase = out + (size_t)b * L_ * C_ + c0;
    for (int r = 0; r < 16; ++r) {
        int tau = (r << 8) + tid;
        float4 acc = make_float4(0.f, 0.f, 0.f, 0.f);
        #pragma unroll
        for (int i = 0; i < K_; ++i) {
            float4 x = sv[(tau + dir[i]) & (L_ - 1)];
            float w = dwr[i];
            acc.x = fmaf(w, x.x, acc.x);
            acc.y = fmaf(w, x.y, acc.y);
            acc.z = fmaf(w, x.z, acc.z);
            acc.w = fmaf(w, x.w, acc.w);
        }
        *(float4*)(obase + (size_t)tau * C_) = acc;
    }
}

extern "C" void kernel_launch(void* const* d_in, const int* in_sizes, int n_in,
                              void* d_out, int out_size, void* d_ws, size_t ws_size,
                              hipStream_t stream) {
    const float* q = (const float*)d_in[0];
    const float* k = (const float*)d_in[1];
    const float* v = (const float*)d_in[2];
    float* out = (float*)d_out;
    char* ws = (char*)d_ws;

    // ws layout: [cross 512KB | mv 256KB | idx | wts]  (no z: fully fused FFT)
    float* cross = (float*)ws;
    float* mv    = (float*)(ws + (1 << 20));
    int*   idx   = (int*)(ws + (1 << 20) + (1 << 18));
    float* wts   = (float*)(ws + (1 << 20) + (1 << 18) + 4096);

    k_zero<<<(B_ * L_ * 2 + 255) / 256, 256, 0, stream>>>(cross, B_ * L_ * 2);
    k_fft1<<<B_ * C_, 256, 0, stream>>>(q, k, cross);
    k_ifft<<<B_, 256, 0, stream>>>(cross, mv);
    k_topk<<<1, 256, 0, stream>>>(mv, idx, wts);
    k_agg<<<B_ * (C_ / 4), 256, 0, stream>>>(v, idx, wts, out);
}

// Round 12
// 642.847 us; speedup vs baseline: 1.0710x; 1.0710x over previous
//
#include <hip/hip_runtime.h>
#include <math.h>

#define B_ 16
#define L_ 4096
#define H_ 8
#define E_ 64
#define C_ 512     // H*E
#define K_ 24
#define NT 256
#define RPAD 257   // padded row stride (float2 units) for the 16x256 LDS matrix
#define WSZ 4112   // 16*RPAD, per-channel FFT work size (float2)
#define PSTRIDE 2052  // partial-spectrum row stride (float2), bins 0..2048 used

__device__ __forceinline__ float2 cmul(float2 a, float2 b) {
    return make_float2(a.x * b.x - a.y * b.y, a.x * b.y + a.y * b.x);
}
__device__ __forceinline__ float2 cadd(float2 a, float2 b) { return make_float2(a.x + b.x, a.y + b.y); }
__device__ __forceinline__ float2 csub(float2 a, float2 b) { return make_float2(a.x - b.x, a.y - b.y); }

// barrier that orders LDS only: each wave drains its own lgkmcnt, then
// s_barrier -> all waves' LDS ops retired; vmcnt loads stay in flight
__device__ __forceinline__ void bar_lds() {
    asm volatile("s_waitcnt lgkmcnt(0)" ::: "memory");
    __builtin_amdgcn_s_barrier();
}

// 16-point DIF FFT, natural-order input; output: X[k] = a[br4[k]]
__device__ __forceinline__ void fft16(float2 a[16]) {
    const float r2 = 0.70710678118654752f;
    const float c1 = 0.92387953251128676f;  // cos(pi/8)
    const float s1 = 0.38268343236508977f;  // sin(pi/8)
    const float2 W16[8] = {
        make_float2(1.f, 0.f),  make_float2(c1, -s1),  make_float2(r2, -r2),  make_float2(s1, -c1),
        make_float2(0.f, -1.f), make_float2(-s1, -c1), make_float2(-r2, -r2), make_float2(-c1, -s1)};
    #pragma unroll
    for (int j = 0; j < 8; ++j) {
        float2 u = a[j], v = a[j + 8];
        a[j]     = cadd(u, v);
        a[j + 8] = cmul(csub(u, v), W16[j]);
    }
    #pragma unroll
    for (int b = 0; b < 16; b += 8)
        #pragma unroll
        for (int j = 0; j < 4; ++j) {
            float2 u = a[b + j], v = a[b + j + 4];
            a[b + j]     = cadd(u, v);
            a[b + j + 4] = cmul(csub(u, v), W16[2 * j]);
        }
    #pragma unroll
    for (int b = 0; b < 16; b += 4)
        #pragma unroll
        for (int j = 0; j < 2; ++j) {
            float2 u = a[b + j], v = a[b + j + 2];
            a[b + j]     = cadd(u, v);
            a[b + j + 2] = cmul(csub(u, v), W16[4 * j]);
        }
    #pragma unroll
    for (int b = 0; b < 16; b += 2) {
        float2 u = a[b], v = a[b + 1];
        a[b]     = cadd(u, v);
        a[b + 1] = csub(u, v);
    }
}

// ---------------- fused forward FFT + cross-spectrum: ONE CHANNEL PER BLOCK ----------------
// Round-11 post-mortem: the device-atomic reduction was the binding constraint
// of ALL fused variants (r7: 16.8M atomics/275us, r8: 16.8M/275us, r11:
// 33.6M/570us -- time tracks atomic count exactly; r11 showed 6x HBM write
// amplification, 785MB for 134MB payload, from 512-way per-bin contention).
// This version: IDENTICAL FFT structure, but the atomic tail is replaced by
// contention-free coalesced partial stores part[b][c][p]; k_reduce sums them.
// FFT structure (r11): 256 threads / 1 channel / 4-wave barriers, 35KB LDS ->
// 4 blocks/CU; stride-8B LDS everywhere -> zero bank conflicts; staging in two
// 8-tau sub-rounds keeps live regs ~55 < 64 (VGPR=52 measured, no scratch).
// Channel pairs (c, c^1) load the same float2; the 16 blocks sharing each 64B
// line map to the same XCD (line index = id bits 3..6; XCD = id&7) -> L2 dedup
// (verified r11: FETCH 200MB vs 256MB raw input).
// Conjugate symmetry: S(L-p)=conj(S(p)) -> only bins 0..2048 stored.
__global__ __launch_bounds__(256) void k_fft1(const float* __restrict__ q,
                                              const float* __restrict__ k,
                                              float2* __restrict__ part) {
    __shared__ float2 w[WSZ];         // 32.9 KB union: stg[0..4095] / RPAD work
    __shared__ float2 tw256[256];     // tw256[r1*16+m2] = W256^{m2*r1}
    const int br4[16] = {0, 8, 4, 12, 2, 10, 6, 14, 1, 9, 5, 13, 3, 11, 7, 15};
    const int t = threadIdx.x;

    // XCD-aware bijective decode: 8192 blocks; xcd = id&7 owns 2 whole batches
    int id = blockIdx.x;
    int wk = ((id & 7) << 10) | (id >> 3);
    int b  = wk >> 9;                 // 0..15
    int c  = wk & 511;                // channel

    {
        int r1 = t >> 4, m2 = t & 15;
        float sn, cs;
        sincospif((float)(r1 * m2) / 128.0f, &sn, &cs);
        tw256[t] = make_float2(cs, -sn);
    }

    const int comp = c & 1;
    const float* qb = q + (size_t)b * L_ * C_ + (c & ~1);
    const float* kb = k + (size_t)b * L_ * C_ + (c & ~1);

    // ---- stage z = q_c + i*k_c into w[tau], two 8-tau sub-rounds (32 regs live)
    #pragma unroll
    for (int sr = 0; sr < 2; ++sr) {
        float2 qv[8], kv[8];
        #pragma unroll
        for (int it = 0; it < 8; ++it) {
            int tau = (((sr << 3) + it) << 8) + t;
            qv[it] = *(const float2*)(qb + (size_t)tau * C_);
            kv[it] = *(const float2*)(kb + (size_t)tau * C_);
        }
        #pragma unroll
        for (int it = 0; it < 8; ++it) {
            int tau = (((sr << 3) + it) << 8) + t;
            float qc = comp ? qv[it].y : qv[it].x;
            float kc = comp ? kv[it].y : kv[it].x;
            w[tau] = make_float2(qc, kc);   // lane-stride 8B: conflict-free
        }
    }
    __syncthreads();

    // ---- phase-A gather (stride 8B, conflict-free) ----
    float2 a[16];
    #pragma unroll
    for (int n1 = 0; n1 < 16; ++n1)
        a[n1] = w[(n1 << 8) + t];
    bar_lds();   // all gathers retired before phase-A writes overwrite stg

    // ---- phase A ----
    fft16(a);
    {
        float snA, csA;
        sincospif((float)t / 2048.0f, &snA, &csA);
        const float2 w1 = make_float2(csA, -snA);
        float2 tw = w1;
        w[t] = a[0];                        // k1 = 0
        #pragma unroll
        for (int k1 = 1; k1 < 16; ++k1) {
            w[k1 * RPAD + t] = cmul(a[br4[k1]], tw);
            tw = cmul(tw, w1);
        }
    }
    __syncthreads();
    // ---- phase B (in-place, cells thread-exclusive) ----
    const int rowB = t >> 4, m2B = t & 15;
    #pragma unroll
    for (int m1 = 0; m1 < 16; ++m1) a[m1] = w[rowB * RPAD + (m1 << 4) + m2B];
    fft16(a);
    #pragma unroll
    for (int r1 = 0; r1 < 16; ++r1)
        w[rowB * RPAD + (r1 << 4) + m2B] = cmul(a[br4[r1]], tw256[(r1 << 4) + m2B]);
    __syncthreads();
    // ---- phase C ----
    const int k1C = t & 15, r1C = t >> 4;
    #pragma unroll
    for (int m2 = 0; m2 < 16; ++m2) a[m2] = w[k1C * RPAD + (r1C << 4) + m2];
    fft16(a);
    __syncthreads();
    #pragma unroll
    for (int r2 = 0; r2 < 16; ++r2)
        w[(r2 << 8) + t] = a[br4[r2]];      // (r1C<<4)|k1C == t: natural order
    bar_lds();

    // ---- unpack Z=Q+iK, S=Q*conj(K), half spectrum; PLAIN coalesced stores ----
    float2* pb = part + (size_t)wk * PSTRIDE;   // part[b][c][*]
    #pragma unroll
    for (int r = 0; r < 8; ++r) {
        int p  = t + (r << 8);
        int pp = (L_ - p) & (L_ - 1);
        float2 A  = w[p];
        float2 Bv = w[pp];
        float Qr = 0.5f * (A.x + Bv.x);
        float Qi = 0.5f * (A.y - Bv.y);
        float Kr = 0.5f * (A.y + Bv.y);
        float Ki = 0.5f * (A.x - Bv.x);
        pb[p] = make_float2(Qr * Kr - Qi * Ki, Qr * Ki + Qi * Kr);
    }
    if (t == 0) pb[2048] = make_float2(w[2048].x * w[2048].y, 0.f);  // Nyquist: real
}

// ---------------- partial-spectrum reduction: cross[b][p] = sum_c part[b][c][p] ----------------
// Grid (16, 17): block = (batch, 128-bin tile). 256 threads: t&127 -> bin,
// t>>7 -> channel half (c-halves summed in LDS). For fixed c, consecutive
// lanes read consecutive bins -> fully coalesced 512B/wave. No atomics.
__global__ __launch_bounds__(256) void k_reduce(const float2* __restrict__ part,
                                                float* __restrict__ cross) {
    __shared__ float2 acc2[128];
    int b  = blockIdx.x;
    int pt = blockIdx.y;
    int t  = threadIdx.x;
    int pi = t & 127, ch = t >> 7;
    int p  = pt * 128 + pi;
    float sx = 0.f, sy = 0.f;
    if (p <= 2048) {
        const float2* base = part + ((size_t)b * C_ + ch * 256) * PSTRIDE + p;
        for (int c = 0; c < 256; ++c) {
            float2 v = base[(size_t)c * PSTRIDE];
            sx += v.x; sy += v.y;
        }
    }
    if (ch == 1) acc2[pi] = make_float2(sx, sy);
    __syncthreads();
    if (ch == 0 && p <= 2048) {
        float2 o = acc2[pi];
        ((float2*)cross)[(size_t)b * L_ + p] = make_float2(sx + o.x, sy + o.y);
    }
}

// ---------------- inverse FFT via conj-forward 3-phase radix-16 ----------------
// cross holds only bins 0..2048; upper half reconstructed via S(L-p)=conj(S(p)).
__global__ __launch_bounds__(256) void k_ifft(const float* __restrict__ cross,
                                              float* __restrict__ mv) {
    __shared__ float2 s[16 * RPAD];
    __shared__ float2 tw256[256];
    const int br4[16] = {0, 8, 4, 12, 2, 10, 6, 14, 1, 9, 5, 13, 3, 11, 7, 15};
    int t = threadIdx.x;
    int b = blockIdx.x;
    {
        int r1 = t >> 4, m2 = t & 15;
        float sn, cs;
        sincospif((float)(r1 * m2) / 128.0f, &sn, &cs);
        tw256[t] = make_float2(cs, -sn);
    }
    const float2* cr = (const float2*)cross + (size_t)b * L_;
    float2 a[16];
    #pragma unroll
    for (int n1 = 0; n1 < 16; ++n1) {
        int P = (n1 << 8) + t;
        int hi = P > 2048;
        float2 v = cr[hi ? (L_ - P) : P];
        // want a = conj(S(P)): P<=2048 -> conj(v); P>2048 -> S(P)=conj(v) -> a = v
        a[n1] = hi ? v : make_float2(v.x, -v.y);
    }
    // ---- phase A ----
    fft16(a);
    {
        float sn, cs;
        sincospif((float)t / 2048.0f, &sn, &cs);
        const float2 w1 = make_float2(cs, -sn);
        float2 tw = w1;
        s[t] = a[0];
        #pragma unroll
        for (int k1 = 1; k1 < 16; ++k1) {
            s[k1 * RPAD + t] = cmul(a[br4[k1]], tw);
            tw = cmul(tw, w1);
        }
    }
    __syncthreads();
    // ---- phase B ----
    const int rowB = t >> 4, m2B = t & 15;
    #pragma unroll
    for (int m1 = 0; m1 < 16; ++m1) a[m1] = s[rowB * RPAD + (m1 << 4) + m2B];
    fft16(a);
    #pragma unroll
    for (int r1 = 0; r1 < 16; ++r1)
        s[rowB * RPAD + (r1 << 4) + m2B] = cmul(a[br4[r1]], tw256[(r1 << 4) + m2B]);
    __syncthreads();
    // ---- phase C: write mv directly (k = r2*256 + t, coalesced) ----
    const int k1C = t & 15, r1C = t >> 4;
    #pragma unroll
    for (int m2 = 0; m2 < 16; ++m2) a[m2] = s[k1C * RPAD + (r1C << 4) + m2];
    fft16(a);
    const float scale = 1.0f / ((float)L_ * (float)C_);
    #pragma unroll
    for (int r2 = 0; r2 < 16; ++r2)
        mv[(size_t)b * L_ + (r2 << 8) + t] = a[br4[r2]].x * scale;
}

// ---------------- top-24 + per-batch softmax (register-resident, wave-shuffle) ----------------
__global__ __launch_bounds__(256) void k_topk(const float* __restrict__ mv,
                                              int* __restrict__ idx,
                                              float* __restrict__ wts) {
    __shared__ float wv[4];
    __shared__ int   wi[4];
    __shared__ int   idxL[K_];
    int tid = threadIdx.x;
    float vloc[16];
    #pragma unroll
    for (int r = 0; r < 16; ++r) {
        int tt = tid + (r << 8);
        float ssum = 0.f;
        for (int b = 0; b < B_; ++b) ssum += mv[(size_t)b * L_ + tt];
        vloc[r] = ssum;
    }
    int lane = tid & 63, w = tid >> 6;
    for (int i = 0; i < K_; ++i) {
        float best = -INFINITY; int bi = 1 << 30;
        #pragma unroll
        for (int r = 0; r < 16; ++r) {
            float v = vloc[r]; int ii = tid + (r << 8);
            if (v > best || (v == best && ii < bi)) { best = v; bi = ii; }
        }
        #pragma unroll
        for (int off = 32; off > 0; off >>= 1) {
            float ov = __shfl_down(best, off);
            int   oi = __shfl_down(bi, off);
            if (ov > best || (ov == best && oi < bi)) { best = ov; bi = oi; }
        }
        if (lane == 0) { wv[w] = best; wi[w] = bi; }
        __syncthreads();
        if (tid == 0) {
            float bb = wv[0]; int bj = wi[0];
            for (int j = 1; j < 4; ++j)
                if (wv[j] > bb || (wv[j] == bb && wi[j] < bj)) { bb = wv[j]; bj = wi[j]; }
            idxL[i] = bj; idx[i] = bj;
        }
        __syncthreads();
        int win = idxL[i];
        #pragma unroll
        for (int r = 0; r < 16; ++r)
            if (win == tid + (r << 8)) vloc[r] = -INFINITY;
    }
    if (tid < B_) {
        int b = tid;
        float ww[K_]; float wm = -INFINITY;
        for (int i = 0; i < K_; ++i) { ww[i] = mv[(size_t)b * L_ + idxL[i]]; wm = fmaxf(wm, ww[i]); }
        float ssum = 0.f;
        for (int i = 0; i < K_; ++i) { ww[i] = expf(ww[i] - wm); ssum += ww[i]; }
        float inv = 1.f / ssum;
        for (int i = 0; i < K_; ++i) wts[b * K_ + i] = ww[i] * inv;
    }
}

// ---------------- 24-tap circulant gather-sum, LDS tau-ring version ----------------
__global__ __launch_bounds__(256) void k_agg(const float* __restrict__ vals,
                                             const int* __restrict__ idx,
                                             const float* __restrict__ wts,
                                             float* __restrict__ out) {
    __shared__ float4 sv[L_];      // 64 KB ring: 2 blocks/CU
    __shared__ int   di[K_];
    __shared__ float dw[K_];
    const int tid = threadIdx.x;
    // XCD-aware bijective decode: 2048 blocks; xcd = id&7 owns work [xcd*256, xcd*256+256)
    int id = blockIdx.x;
    int wk = ((id & 7) << 8) | (id >> 3);
    int b  = wk >> 7;              // 0..15 (2 batches per XCD)
    int c0 = (wk & 127) << 2;      // channel-quad start

    if (tid < K_) { di[tid] = idx[tid]; dw[tid] = wts[b * K_ + tid]; }

    // ---- stage: 16 iters x 256 lanes x 16B, LDS dest linear (wave-uniform base + lane*16)
    const float* gbase = vals + (size_t)b * L_ * C_ + c0;
    #pragma unroll
    for (int it = 0; it < 16; ++it) {
        int tau = (it << 8) + tid;
        const float* g = gbase + (size_t)tau * C_;
        float4* l = &sv[(it << 8) + ((tid >> 6) << 6)];   // wave-uniform within each wave
        __builtin_amdgcn_global_load_lds(
            (const __attribute__((address_space(1))) uint32_t*)g,
            (__attribute__((address_space(3))) uint32_t*)l,
            16, 0, 0);
    }
    __syncthreads();   // drains vmcnt before barrier

    // taps/weights to registers (fully-unrolled static indexing)
    int   dir[K_]; float dwr[K_];
    #pragma unroll
    for (int i = 0; i < K_; ++i) { dir[i] = di[i]; dwr[i] = dw[i]; }

    float* obase = out + (size_t)b * L_ * C_ + c0;
    for (int r = 0; r < 16; ++r) {
        int tau = (r << 8) + tid;
        float4 acc = make_float4(0.f, 0.f, 0.f, 0.f);
        #pragma unroll
        for (int i = 0; i < K_; ++i) {
            float4 x = sv[(tau + dir[i]) & (L_ - 1)];
            float w = dwr[i];
            acc.x = fmaf(w, x.x, acc.x);
            acc.y = fmaf(w, x.y, acc.y);
            acc.z = fmaf(w, x.z, acc.z);
            acc.w = fmaf(w, x.w, acc.w);
        }
        *(float4*)(obase + (size_t)tau * C_) = acc;
    }
}

extern "C" void kernel_launch(void* const* d_in, const int* in_sizes, int n_in,
                              void* d_out, int out_size, void* d_ws, size_t ws_size,
                              hipStream_t stream) {
    const float* q = (const float*)d_in[0];
    const float* k = (const float*)d_in[1];
    const float* v = (const float*)d_in[2];
    float* out = (float*)d_out;
    char* ws = (char*)d_ws;

    // ws layout: [cross 512KB | mv 256KB | idx | wts | ... | part at 2MB (134.5MB)]
    float*  cross = (float*)ws;
    float*  mv    = (float*)(ws + (1 << 20));
    int*    idx   = (int*)(ws + (1 << 20) + (1 << 18));
    float*  wts   = (float*)(ws + (1 << 20) + (1 << 18) + 4096);
    float2* part  = (float2*)(ws + (2 << 20));

    k_fft1<<<B_ * C_, 256, 0, stream>>>(q, k, part);
    dim3 gr(B_, 17);
    k_reduce<<<gr, 256, 0, stream>>>(part, cross);
    k_ifft<<<B_, 256, 0, stream>>>(cross, mv);
    k_topk<<<1, 256, 0, stream>>>(mv, idx, wts);
    k_agg<<<B_ * (C_ / 4), 256, 0, stream>>>(v, idx, wts, out);
}

// Round 13
// 329.212 us; speedup vs baseline: 2.0913x; 1.9527x over previous
//
#include <hip/hip_runtime.h>
#include <math.h>

#define B_ 16
#define L_ 4096
#define H_ 8
#define E_ 64
#define C_ 512     // H*E
#define K_ 24
#define NT 256
#define RPAD 257      // padded row stride (float2 units) for the 16x256 LDS matrix
#define PSTRIDE 2052  // partial-spectrum row stride (float2), bins 0..2048 used
#define G_ 64         // channel groups (8 ch each) per batch

__device__ __forceinline__ float2 cmul(float2 a, float2 b) {
    return make_float2(a.x * b.x - a.y * b.y, a.x * b.y + a.y * b.x);
}
__device__ __forceinline__ float2 cadd(float2 a, float2 b) { return make_float2(a.x + b.x, a.y + b.y); }
__device__ __forceinline__ float2 csub(float2 a, float2 b) { return make_float2(a.x - b.x, a.y - b.y); }

// barrier that orders LDS only: does NOT drain vmcnt, so register prefetch
// loads stay in flight across it (no cross-thread global deps at these points)
__device__ __forceinline__ void bar_lds() {
    asm volatile("s_waitcnt lgkmcnt(0)" ::: "memory");
    __builtin_amdgcn_s_barrier();
}

// 16-point DIF FFT, natural-order input; output: X[k] = a[br4[k]]
__device__ __forceinline__ void fft16(float2 a[16]) {
    const float r2 = 0.70710678118654752f;
    const float c1 = 0.92387953251128676f;  // cos(pi/8)
    const float s1 = 0.38268343236508977f;  // sin(pi/8)
    const float2 W16[8] = {
        make_float2(1.f, 0.f),  make_float2(c1, -s1),  make_float2(r2, -r2),  make_float2(s1, -c1),
        make_float2(0.f, -1.f), make_float2(-s1, -c1), make_float2(-r2, -r2), make_float2(-c1, -s1)};
    #pragma unroll
    for (int j = 0; j < 8; ++j) {
        float2 u = a[j], v = a[j + 8];
        a[j]     = cadd(u, v);
        a[j + 8] = cmul(csub(u, v), W16[j]);
    }
    #pragma unroll
    for (int b = 0; b < 16; b += 8)
        #pragma unroll
        for (int j = 0; j < 4; ++j) {
            float2 u = a[b + j], v = a[b + j + 4];
            a[b + j]     = cadd(u, v);
            a[b + j + 4] = cmul(csub(u, v), W16[2 * j]);
        }
    #pragma unroll
    for (int b = 0; b < 16; b += 4)
        #pragma unroll
        for (int j = 0; j < 2; ++j) {
            float2 u = a[b + j], v = a[b + j + 2];
            a[b + j]     = cadd(u, v);
            a[b + j + 2] = cmul(csub(u, v), W16[4 * j]);
        }
    #pragma unroll
    for (int b = 0; b < 16; b += 2) {
        float2 u = a[b], v = a[b + 1];
        a[b]     = cadd(u, v);
        a[b + 1] = csub(u, v);
    }
}

// ---------------- fused transpose + FFT phase A (four-step split) ----------------
// r12 lesson: split beats fusion — fusion's column-gather staging touches 64
// distinct lines per wave-load (per-CU L1 fill serialization); this kernel's
// 4-lane-per-row float4 loads touch 16. The z round-trip (512MB, ~81us at BW)
// is cheaper than fusion's staging penalty (measured 250us+).
// n = n1*256 + n2. Block = (n2 window of 16) x (16 channels) x batch.
// Twiddle W4096^{n2*k1}: 4 independent recurrence chains (depth 15 -> 6; r3
// ran VALUBusy 18% = latency-bound, the serial 15-cmul chain was on the
// critical path between stores).
__global__ __launch_bounds__(256) void k_phaseA(const float* __restrict__ q,
                                                const float* __restrict__ k,
                                                float2* __restrict__ z,
                                                int b0) {
    __shared__ float2 s2[256 * 17];   // [row = n1*16 + n2loc][ch], stride 17 -> 34.8 KB
    const int br4[16] = {0, 8, 4, 12, 2, 10, 6, 14, 1, 9, 5, 13, 3, 11, 7, 15};
    int w  = blockIdx.x;              // n2 window (16 of them)
    int g  = blockIdx.y;              // channel group of 16 (32 of them)
    int bl = blockIdx.z;
    int b  = b0 + bl;
    int tid = threadIdx.x;

    // ---- load 256 rows x 16 ch, float4 per (row, quad): 16 lines/wave-load ----
    const size_t base = (size_t)b * L_ * C_ + g * 16;
    int lrow = tid >> 2;              // 0..63
    int lq   = tid & 3;               // quad within 16 channels
    #pragma unroll
    for (int it = 0; it < 4; ++it) {
        int r   = lrow + (it << 6);                     // row = n1*16 + n2loc
        int tau = ((r >> 4) << 8) + (w << 4) + (r & 15);
        const float4 q4 = *(const float4*)(q + base + (size_t)tau * C_ + (lq << 2));
        const float4 k4 = *(const float4*)(k + base + (size_t)tau * C_ + (lq << 2));
        float2* dst = &s2[r * 17 + (lq << 2)];
        dst[0] = make_float2(q4.x, k4.x);
        dst[1] = make_float2(q4.y, k4.y);
        dst[2] = make_float2(q4.z, k4.z);
        dst[3] = make_float2(q4.w, k4.w);
    }
    __syncthreads();

    // ---- compute: thread = (ch = tid>>4, n2loc = tid&15) ----
    int ch = tid >> 4, n2loc = tid & 15;
    int n2 = (w << 4) + n2loc;
    float2 a[16];
    int rbase = n2loc * 17 + ch;
    #pragma unroll
    for (int n1 = 0; n1 < 16; ++n1) a[n1] = s2[n1 * 272 + rbase];
    fft16(a);
    // twiddle W4096^{n2*k1}: 4 independent chains stepped by w4 = W^{4*n2}
    float sn, cs;
    sincospif((float)n2 / 2048.0f, &sn, &cs);
    const float2 w1 = make_float2(cs, -sn);
    const float2 w2 = cmul(w1, w1);
    const float2 w4 = cmul(w2, w2);
    float2 tws[4] = {w1, w2, cmul(w2, w1), w4};
    float2* zc = z + ((size_t)bl * C_ + (g * 16 + ch)) * L_ + n2;
    zc[0] = a[0];                      // k1 = 0 (br4[0]=0, tw=1)
    #pragma unroll
    for (int k1 = 1; k1 < 16; ++k1) {
        int j = (k1 - 1) & 3;
        zc[(size_t)(k1 << 8)] = cmul(a[br4[k1]], tws[j]);
        tws[j] = cmul(tws[j], w4);
    }
}

// ---------------- FFT phases B+C + cross-spectrum accumulate (half spectrum) ----------------
// z[c][k1*256+n2] holds phase-A output (twiddled). Thread t: rowB = t>>4 = k1,
// m2B = t&15. Phase B: DFT16 over m1, twiddle W256^{m2*r1}. Phase C: DFT16
// over m2 -> natural-order X. Conjugate symmetry S(L-p)=conj(S(p)) (Q,K real)
// -> accumulate only bins 0..2047 + Nyquist. Tail: contention-free partial
// stores part[b*64+g][p] (r11/r12 lesson: device atomics at >=8M lanes are the
// binding constraint — time tracked atomic count exactly across r7/r8/r11).
// Next channel's z prefetched into dead a[] across the accumulate phase.
__global__ __launch_bounds__(256) void k_fft_bc(const float2* __restrict__ z,
                                                float2* __restrict__ part,
                                                int b0) {
    __shared__ float2 s[16 * RPAD];
    __shared__ float2 tw256[256];     // tw256[r1*16+m2] = W256^{m2*r1}
    const int br4[16] = {0, 8, 4, 12, 2, 10, 6, 14, 1, 9, 5, 13, 3, 11, 7, 15};
    int t  = threadIdx.x;
    int bl = blockIdx.y;
    int b  = b0 + bl;
    int g  = blockIdx.x;              // channel group of 8
    int c0 = g * 8;

    {
        int r1 = t >> 4, m2 = t & 15;
        float sn, cs;
        sincospif((float)(r1 * m2) / 128.0f, &sn, &cs);
        tw256[t] = make_float2(cs, -sn);
    }
    float accx[8], accy[8], accN = 0.f;
    #pragma unroll
    for (int r = 0; r < 8; ++r) { accx[r] = 0.f; accy[r] = 0.f; }

    const int rowB = t >> 4, m2B = t & 15;
    const int k1C = t & 15, r1C = t >> 4;

    // prefetch channel 0 (stays in flight across the setup barrier)
    float2 a[16];
    {
        const float2* zc0 = z + ((size_t)bl * C_ + c0) * L_;
        #pragma unroll
        for (int m1 = 0; m1 < 16; ++m1) a[m1] = zc0[(rowB << 8) + (m1 << 4) + m2B];
    }
    bar_lds();   // tw256 ready

    for (int cc = 0; cc < 8; ++cc) {
        // ---- phase B (input prefetched in a[]) ----
        fft16(a);
        #pragma unroll
        for (int r1 = 0; r1 < 16; ++r1)
            s[rowB * RPAD + (r1 << 4) + m2B] = cmul(a[br4[r1]], tw256[(r1 << 4) + m2B]);
        __syncthreads();
        // ---- phase C ----
        #pragma unroll
        for (int m2 = 0; m2 < 16; ++m2) a[m2] = s[k1C * RPAD + (r1C << 4) + m2];
        fft16(a);
        __syncthreads();
        #pragma unroll
        for (int r2 = 0; r2 < 16; ++r2)
            s[(r2 << 8) + (r1C << 4) + k1C] = a[br4[r2]];   // natural order, flat
        // ---- prefetch next channel into now-dead a[] ----
        if (cc < 7) {
            const float2* zn = z + ((size_t)bl * C_ + (c0 + cc + 1)) * L_;
            #pragma unroll
            for (int m1 = 0; m1 < 16; ++m1) a[m1] = zn[(rowB << 8) + (m1 << 4) + m2B];
        }
        bar_lds();   // LDS-ordering only; prefetch stays in flight
        // ---- unpack Z=Q+iK, accumulate Q*conj(K), bins 0..2047 + Nyquist ----
        #pragma unroll
        for (int r = 0; r < 8; ++r) {
            int p  = t + (r << 8);
            int pp = (L_ - p) & (L_ - 1);
            float2 A  = s[p];
            float2 Bv = s[pp];
            float Qr = 0.5f * (A.x + Bv.x);
            float Qi = 0.5f * (A.y - Bv.y);
            float Kr = 0.5f * (A.y + Bv.y);
            float Ki = 0.5f * (A.x - Bv.x);
            accx[r] += Qr * Kr - Qi * Ki;
            accy[r] += Qr * Ki + Qi * Kr;
        }
        accN += s[2048].x * s[2048].y;  // Nyquist: Q,K real there (LDS broadcast)
        bar_lds();   // accum reads done before next phase B overwrites s
    }
    // ---- contention-free coalesced partial stores (no atomics) ----
    float2* pb = part + (size_t)(b * G_ + g) * PSTRIDE;
    #pragma unroll
    for (int r = 0; r < 8; ++r)
        pb[t + (r << 8)] = make_float2(accx[r], accy[r]);
    if (t == 0) pb[2048] = make_float2(accN, 0.f);
}

// ---------------- partial-spectrum reduction: cross[b][p] = sum_g part[b][g][p] ----------------
// Grid (16, 17): block = (batch, 128-bin tile). t&127 -> bin, t>>7 -> group
// half (32 groups each, halves combined in LDS). Coalesced reads, no atomics.
__global__ __launch_bounds__(256) void k_reduce(const float2* __restrict__ part,
                                                float* __restrict__ cross) {
    __shared__ float2 acc2[128];
    int b  = blockIdx.x;
    int pt = blockIdx.y;
    int t  = threadIdx.x;
    int pi = t & 127, gh = t >> 7;
    int p  = pt * 128 + pi;
    float sx = 0.f, sy = 0.f;
    if (p <= 2048) {
        const float2* base = part + ((size_t)b * G_ + gh * 32) * PSTRIDE + p;
        #pragma unroll 4
        for (int g = 0; g < 32; ++g) {
            float2 v = base[(size_t)g * PSTRIDE];
            sx += v.x; sy += v.y;
        }
    }
    if (gh == 1) acc2[pi] = make_float2(sx, sy);
    __syncthreads();
    if (gh == 0 && p <= 2048) {
        float2 o = acc2[pi];
        ((float2*)cross)[(size_t)b * L_ + p] = make_float2(sx + o.x, sy + o.y);
    }
}

// ---------------- inverse FFT via conj-forward 3-phase radix-16 ----------------
// cross holds only bins 0..2048; upper half reconstructed via S(L-p)=conj(S(p)).
__global__ __launch_bounds__(256) void k_ifft(const float* __restrict__ cross,
                                              float* __restrict__ mv) {
    __shared__ float2 s[16 * RPAD];
    __shared__ float2 tw256[256];
    const int br4[16] = {0, 8, 4, 12, 2, 10, 6, 14, 1, 9, 5, 13, 3, 11, 7, 15};
    int t = threadIdx.x;
    int b = blockIdx.x;
    {
        int r1 = t >> 4, m2 = t & 15;
        float sn, cs;
        sincospif((float)(r1 * m2) / 128.0f, &sn, &cs);
        tw256[t] = make_float2(cs, -sn);
    }
    const float2* cr = (const float2*)cross + (size_t)b * L_;
    float2 a[16];
    #pragma unroll
    for (int n1 = 0; n1 < 16; ++n1) {
        int P = (n1 << 8) + t;
        int hi = P > 2048;
        float2 v = cr[hi ? (L_ - P) : P];
        // want a = conj(S(P)): P<=2048 -> conj(v); P>2048 -> S(P)=conj(v) -> a = v
        a[n1] = hi ? v : make_float2(v.x, -v.y);
    }
    // ---- phase A ----
    fft16(a);
    {
        float sn, cs;
        sincospif((float)t / 2048.0f, &sn, &cs);
        const float2 w1 = make_float2(cs, -sn);
        float2 tw = w1;
        s[t] = a[0];
        #pragma unroll
        for (int k1 = 1; k1 < 16; ++k1) {
            s[k1 * RPAD + t] = cmul(a[br4[k1]], tw);
            tw = cmul(tw, w1);
        }
    }
    __syncthreads();
    // ---- phase B ----
    const int rowB = t >> 4, m2B = t & 15;
    #pragma unroll
    for (int m1 = 0; m1 < 16; ++m1) a[m1] = s[rowB * RPAD + (m1 << 4) + m2B];
    fft16(a);
    #pragma unroll
    for (int r1 = 0; r1 < 16; ++r1)
        s[rowB * RPAD + (r1 << 4) + m2B] = cmul(a[br4[r1]], tw256[(r1 << 4) + m2B]);
    __syncthreads();
    // ---- phase C: write mv directly (k = r2*256 + t, coalesced) ----
    const int k1C = t & 15, r1C = t >> 4;
    #pragma unroll
    for (int m2 = 0; m2 < 16; ++m2) a[m2] = s[k1C * RPAD + (r1C << 4) + m2];
    fft16(a);
    const float scale = 1.0f / ((float)L_ * (float)C_);
    #pragma unroll
    for (int r2 = 0; r2 < 16; ++r2)
        mv[(size_t)b * L_ + (r2 << 8) + t] = a[br4[r2]].x * scale;
}

// ---------------- top-24 + per-batch softmax (register-resident, wave-shuffle) ----------------
__global__ __launch_bounds__(256) void k_topk(const float* __restrict__ mv,
                                              int* __restrict__ idx,
                                              float* __restrict__ wts) {
    __shared__ float wv[4];
    __shared__ int   wi[4];
    __shared__ int   idxL[K_];
    int tid = threadIdx.x;
    float vloc[16];
    #pragma unroll
    for (int r = 0; r < 16; ++r) {
        int tt = tid + (r << 8);
        float ssum = 0.f;
        for (int b = 0; b < B_; ++b) ssum += mv[(size_t)b * L_ + tt];
        vloc[r] = ssum;
    }
    int lane = tid & 63, w = tid >> 6;
    for (int i = 0; i < K_; ++i) {
        float best = -INFINITY; int bi = 1 << 30;
        #pragma unroll
        for (int r = 0; r < 16; ++r) {
            float v = vloc[r]; int ii = tid + (r << 8);
            if (v > best || (v == best && ii < bi)) { best = v; bi = ii; }
        }
        #pragma unroll
        for (int off = 32; off > 0; off >>= 1) {
            float ov = __shfl_down(best, off);
            int   oi = __shfl_down(bi, off);
            if (ov > best || (ov == best && oi < bi)) { best = ov; bi = oi; }
        }
        if (lane == 0) { wv[w] = best; wi[w] = bi; }
        __syncthreads();
        if (tid == 0) {
            float bb = wv[0]; int bj = wi[0];
            for (int j = 1; j < 4; ++j)
                if (wv[j] > bb || (wv[j] == bb && wi[j] < bj)) { bb = wv[j]; bj = wi[j]; }
            idxL[i] = bj; idx[i] = bj;
        }
        __syncthreads();
        int win = idxL[i];
        #pragma unroll
        for (int r = 0; r < 16; ++r)
            if (win == tid + (r << 8)) vloc[r] = -INFINITY;
    }
    if (tid < B_) {
        int b = tid;
        float ww[K_]; float wm = -INFINITY;
        for (int i = 0; i < K_; ++i) { ww[i] = mv[(size_t)b * L_ + idxL[i]]; wm = fmaxf(wm, ww[i]); }
        float ssum = 0.f;
        for (int i = 0; i < K_; ++i) { ww[i] = expf(ww[i] - wm); ssum += ww[i]; }
        float inv = 1.f / ssum;
        for (int i = 0; i < K_; ++i) wts[b * K_ + i] = ww[i] * inv;
    }
}

// ---------------- 24-tap circulant gather-sum, LDS tau-ring version ----------------
__global__ __launch_bounds__(256) void k_agg(const float* __restrict__ vals,
                                             const int* __restrict__ idx,
                                             const float* __restrict__ wts,
                                             float* __restrict__ out) {
    __shared__ float4 sv[L_];      // 64 KB ring: 2 blocks/CU
    __shared__ int   di[K_];
    __shared__ float dw[K_];
    const int tid = threadIdx.x;
    // XCD-aware bijective decode: 2048 blocks; xcd = id&7 owns work [xcd*256, xcd*256+256)
    int id = blockIdx.x;
    int wk = ((id & 7) << 8) | (id >> 3);
    int b  = wk >> 7;              // 0..15 (2 batches per XCD)
    int c0 = (wk & 127) << 2;      // channel-quad start

    if (tid < K_) { di[tid] = idx[tid]; dw[tid] = wts[b * K_ + tid]; }

    // ---- stage: 16 iters x 256 lanes x 16B, LDS dest linear (wave-uniform base + lane*16)
    const float* gbase = vals + (size_t)b * L_ * C_ + c0;
    #pragma unroll
    for (int it = 0; it < 16; ++it) {
        int tau = (it << 8) + tid;
        const float* g = gbase + (size_t)tau * C_;
        float4* l = &sv[(it << 8) + ((tid >> 6) << 6)];   // wave-uniform within each wave
        __builtin_amdgcn_global_load_lds(
            (const __attribute__((address_space(1))) uint32_t*)g,
            (__attribute__((address_space(3))) uint32_t*)l,
            16, 0, 0);
    }
    __syncthreads();   // drains vmcnt before barrier

    // taps/weights to registers (fully-unrolled static indexing)
    int   dir[K_]; float dwr[K_];
    #pragma unroll
    for (int i = 0; i < K_; ++i) { dir[i] = di[i]; dwr[i] = dw[i]; }

    float* obase = out + (size_t)b * L_ * C_ + c0;
    for (int r = 0; r < 16; ++r) {
        int tau = (r << 8) + tid;
        float4 acc = make_float4(0.f, 0.f, 0.f, 0.f);
        #pragma unroll
        for (int i = 0; i < K_; ++i) {
            float4 x = sv[(tau + dir[i]) & (L_ - 1)];
            float w = dwr[i];
            acc.x = fmaf(w, x.x, acc.x);
            acc.y = fmaf(w, x.y, acc.y);
            acc.z = fmaf(w, x.z, acc.z);
            acc.w = fmaf(w, x.w, acc.w);
        }
        *(float4*)(obase + (size_t)tau * C_) = acc;
    }
}

extern "C" void kernel_launch(void* const* d_in, const int* in_sizes, int n_in,
                              void* d_out, int out_size, void* d_ws, size_t ws_size,
                              hipStream_t stream) {
    const float* q = (const float*)d_in[0];
    const float* k = (const float*)d_in[1];
    const float* v = (const float*)d_in[2];
    float* out = (float*)d_out;
    char* ws = (char*)d_ws;

    // ws layout: [cross 512KB | mv 256KB | idx | wts | part at 2MB (16.8MB) | z at 20MB]
    float*  cross = (float*)ws;
    float*  mv    = (float*)(ws + (1 << 20));
    int*    idx   = (int*)(ws + (1 << 20) + (1 << 18));
    float*  wts   = (float*)(ws + (1 << 20) + (1 << 18) + 4096);
    float2* part  = (float2*)(ws + (2 << 20));
    float2* z     = (float2*)(ws + (size_t)(20 << 20));

    size_t zcap = (ws_size > (size_t)(20 << 20)) ? ws_size - (size_t)(20 << 20) : 0;
    int P = 16;
    while (P > 1 && (size_t)P * C_ * L_ * sizeof(float2) > zcap) P >>= 1;

    for (int b0 = 0; b0 < B_; b0 += P) {
        dim3 g1(16, 32, P);   // n2 windows x ch groups x batches
        k_phaseA<<<g1, 256, 0, stream>>>(q, k, z, b0);
        dim3 g2(G_, P);
        k_fft_bc<<<g2, 256, 0, stream>>>(z, part, b0);
    }
    dim3 gr(B_, 17);
    k_reduce<<<gr, 256, 0, stream>>>(part, cross);
    k_ifft<<<B_, 256, 0, stream>>>(cross, mv);
    k_topk<<<1, 256, 0, stream>>>(mv, idx, wts);
    k_agg<<<B_ * (C_ / 4), 256, 0, stream>>>(v, idx, wts, out);
}